// Round 11
// baseline (113.396 us; speedup 1.0000x reference)
//
#include <hip/hip_runtime.h>
#include <hip/hip_bf16.h>
#include <math.h>

#define BB 4
#define CC 64
#define DD 8
#define NN 4096
#define KS 8
#define KPS (NN / KS)          // 512 keys per split (2 phases of 256)
#define VSTR 260               // VS row stride (elems): 2-way-free, 8B-aligned reads
#define KSTR 12                // KL row stride (elems)
#define LOG2E 1.44269504088896340736f

typedef __attribute__((ext_vector_type(4))) short short4v;      // 4 bf16
typedef __attribute__((ext_vector_type(4))) unsigned short ushort4v;
typedef __attribute__((ext_vector_type(8))) unsigned short ushort8;  // 16B
typedef __attribute__((ext_vector_type(16))) float f32x16;

#if defined(__HIP_DEVICE_COMPILE__)
  #if __has_builtin(__builtin_amdgcn_mfma_f32_32x32x8bf16_1k)
    #define MFMA32x8(A, B, C) __builtin_amdgcn_mfma_f32_32x32x8bf16_1k(A, B, C, 0, 0, 0)
  #elif __has_builtin(__builtin_amdgcn_mfma_f32_32x32x8_bf16)
    #define MFMA32x8(A, B, C) __builtin_amdgcn_mfma_f32_32x32x8_bf16(A, B, C, 0, 0, 0)
  #else
    #error "no 32x32x8 bf16 MFMA builtin in device pass"
  #endif
  #if __has_builtin(__builtin_amdgcn_exp2f)
    #define EXP2(x) __builtin_amdgcn_exp2f(x)
  #else
    #define EXP2(x) exp2f(x)
  #endif
#else
  static __device__ __host__ inline f32x16 MFMA32x8(short4v, short4v, f32x16 c) { return c; }
  #define EXP2(x) exp2f(x)
#endif

static __device__ inline short4v pack4(float a, float b, float c, float d) {
    union { short4v s; __hip_bfloat162 h[2]; } u;
    u.h[0] = __float22bfloat162_rn(make_float2(a, b));
    u.h[1] = __float22bfloat162_rn(make_float2(c, d));
    return u.s;
}
static __device__ inline unsigned packu(float lo, float hi) {
    union { __hip_bfloat162 h; unsigned u; } t;
    t.h = __float22bfloat162_rn(make_float2(lo, hi));
    return t.u;
}

// ---------------------------------------------------------------------------
// Kernel 1: qkv as MFMA GEMM (unchanged from R8/R10).
// ---------------------------------------------------------------------------
__global__ __launch_bounds__(256) void qkv_kernel(
    const float* __restrict__ x,  const float* __restrict__ Wq, const float* __restrict__ bq,
    const float* __restrict__ Wk, const float* __restrict__ bk,
    const float* __restrict__ Wv, const float* __restrict__ bv,
    unsigned short* __restrict__ qb, unsigned short* __restrict__ kb,
    unsigned short* __restrict__ vT)
{
    __shared__ unsigned short LQ[128 * 8];
    __shared__ unsigned short LK[128 * 8];

    int tid = threadIdx.x;
    int wave = tid >> 6, lane = tid & 63;
    int l32 = lane & 31, h2 = lane >> 5;

    int blk = blockIdx.x;
    int b = blk & (BB - 1);
    int r2 = blk >> 2;
    int rt = r2 % 3;
    int ng = r2 / 3;
    int n0 = ng * 128 + wave * 32;

    short4v af[8];
    #pragma unroll
    for (int s = 0; s < 8; ++s) {
        float4 w4;
        if (rt < 2) {
            w4 = *(const float4*)(Wv + (size_t)(rt * 32 + l32) * CC + s * 8 + 4 * h2);
        } else if (l32 < 8) {
            w4 = *(const float4*)(Wq + (size_t)l32 * CC + s * 8 + 4 * h2);
        } else if (l32 < 16) {
            w4 = *(const float4*)(Wk + (size_t)(l32 - 8) * CC + s * 8 + 4 * h2);
        } else {
            w4 = make_float4(0.f, 0.f, 0.f, 0.f);
        }
        af[s] = pack4(w4.x, w4.y, w4.z, w4.w);
    }

    const float* xb = x + (size_t)b * CC * NN + n0 + l32;
    short4v bf[8];
    #pragma unroll
    for (int s = 0; s < 8; ++s) {
        int c0 = s * 8 + 4 * h2;
        float x0 = xb[(size_t)(c0 + 0) * NN];
        float x1 = xb[(size_t)(c0 + 1) * NN];
        float x2 = xb[(size_t)(c0 + 2) * NN];
        float x3 = xb[(size_t)(c0 + 3) * NN];
        bf[s] = pack4(x0, x1, x2, x3);
    }

    f32x16 acc;
    #pragma unroll
    for (int r = 0; r < 16; ++r) acc[r] = 0.f;
    #pragma unroll
    for (int s = 0; s < 8; ++s)
        acc = MFMA32x8(af[s], bf[s], acc);

    if (rt < 2) {
        #pragma unroll
        for (int r = 0; r < 16; ++r) {
            int row = rt * 32 + (r & 3) + 8 * (r >> 2) + 4 * h2;
            float val = acc[r] + bv[row];
            __hip_bfloat16 hv = __float2bfloat16(val);
            vT[((size_t)b * CC + row) * NN + n0 + l32] = *(unsigned short*)&hv;
        }
    } else {
        short4v qp = pack4((acc[0] + bq[0 + 4 * h2]) * LOG2E,
                           (acc[1] + bq[1 + 4 * h2]) * LOG2E,
                           (acc[2] + bq[2 + 4 * h2]) * LOG2E,
                           (acc[3] + bq[3 + 4 * h2]) * LOG2E);
        short4v kp = pack4(acc[4] + bk[0 + 4 * h2],
                           acc[5] + bk[1 + 4 * h2],
                           acc[6] + bk[2 + 4 * h2],
                           acc[7] + bk[3 + 4 * h2]);
        int nl = wave * 32 + l32;
        *(short4v*)(LQ + (size_t)nl * 8 + 4 * h2) = qp;
        *(short4v*)(LK + (size_t)nl * 8 + 4 * h2) = kp;
        __syncthreads();
        if (tid < 128) {
            ushort8 row = *(const ushort8*)(LQ + (size_t)tid * 8);
            *(ushort8*)(qb + ((size_t)b * NN + ng * 128 + tid) * 8) = row;
        } else {
            int t = tid - 128;
            ushort8 row = *(const ushort8*)(LK + (size_t)t * 8);
            *(ushort8*)(kb + ((size_t)b * NN + ng * 128 + t) * 8) = row;
        }
    }
}

// ---------------------------------------------------------------------------
// Kernel 2: MFMA flash, 512-key split in TWO 256-key LDS phases:
// 3 barriers per block TOTAL (vs 8-16 before).  V and K both staged in LDS
// (V stride 260: 2-way-free b64 reads; K stride 12: 2-way free).  Phase-B
// global loads issue right after barrier-A, ds_write after compute-A.
// Stores are RAW-LAYOUT full lines: uint = bf162(o0[r],o1[r]) at
// [group][r][lane] -> 256B contiguous per instr (kills the 4x write
// amplification seen in R7-R10: WRITE_SIZE 34MB for an 8.4MB accb).
// Grid: BB * (N/128) * KS = 1024 blocks, 4/CU (LDS 39.4KB).
// ---------------------------------------------------------------------------
__global__ __launch_bounds__(256, 4) void flash_kernel(
    const unsigned short* __restrict__ qb, const unsigned short* __restrict__ kb,
    const unsigned short* __restrict__ vT, unsigned* __restrict__ accb,
    float* __restrict__ sbuf)
{
    __shared__ unsigned short VS[64 * VSTR];   // 33280 B
    __shared__ unsigned short KL[256 * KSTR];  //  6144 B
    int tid = threadIdx.x;
    int wave = tid >> 6, lane = tid & 63;
    int l32 = lane & 31, h2 = lane >> 5;

    int blk = blockIdx.x;            // batch in low 2 bits -> XCD locality
    int b = blk & (BB - 1);
    int rest = blk >> 2;
    int split = rest & (KS - 1);
    int qchunk = rest >> 3;
    int n0 = qchunk * 128 + wave * 32;

    short4v qf = *(const short4v*)(qb + ((size_t)b * NN + n0 + l32) * DD + h2 * 4);

    const unsigned short* kbb = kb + (size_t)b * NN * DD;
    const unsigned short* vbb = vT + (size_t)b * CC * NN;
    int m0 = split * KPS;

    // staging geometry: wave covers channels [wave*16, wave*16+16);
    // instr i: rows wave*16+2i+h2, lane granule g=l32 (32 granules x 8 keys)
    int chb = wave * 16 + h2;

    f32x16 o0, o1, zz;
    #pragma unroll
    for (int r = 0; r < 16; ++r) { o0[r] = 0.f; o1[r] = 0.f; zz[r] = 0.f; }
    float s0 = 0.f, s1 = 0.f, s2 = 0.f, s3 = 0.f;

    // ---- phase A loads + LDS fill
    ushort8 vA[8];
    #pragma unroll
    for (int i = 0; i < 8; ++i)
        vA[i] = *(const ushort8*)(vbb + (size_t)(chb + 2 * i) * NN + m0 + l32 * 8);
    ushort8 kA = *(const ushort8*)(kbb + (size_t)(m0 + tid) * DD);
    #pragma unroll
    for (int i = 0; i < 8; ++i) {
        unsigned short* p = VS + (size_t)(chb + 2 * i) * VSTR + l32 * 8;
        *(ushort4v*)(p)     = *(ushort4v*)&vA[i];
        *(ushort4v*)(p + 4) = *((ushort4v*)&vA[i] + 1);
    }
    {
        unsigned short* p = KL + (size_t)tid * KSTR;
        *(ushort4v*)(p)     = *(ushort4v*)&kA;
        *(ushort4v*)(p + 4) = *((ushort4v*)&kA + 1);
    }
    __syncthreads();                                   // barrier 1: A ready

    // ---- prefetch phase B (consumed after barrier 2)
    int mB = m0 + 256;
    ushort8 vB[8];
    #pragma unroll
    for (int i = 0; i < 8; ++i)
        vB[i] = *(const ushort8*)(vbb + (size_t)(chb + 2 * i) * NN + mB + l32 * 8);
    ushort8 kB = *(const ushort8*)(kbb + (size_t)(mB + tid) * DD);

    #pragma unroll
    for (int ph = 0; ph < 2; ++ph) {
        #pragma unroll
        for (int s = 0; s < 8; ++s) {
            short4v kf = *(const short4v*)(KL + (size_t)(s * 32 + l32) * KSTR + h2 * 4);
            f32x16 st = MFMA32x8(kf, qf, zz);
            float w[16];
            #pragma unroll
            for (int r = 0; r < 16; ++r) w[r] = EXP2(st[r]);
            s0 += (w[0] + w[1]) + (w[2] + w[3]);
            s1 += (w[4] + w[5]) + (w[6] + w[7]);
            s2 += (w[8] + w[9]) + (w[10] + w[11]);
            s3 += (w[12] + w[13]) + (w[14] + w[15]);

            union { short4v s; __hip_bfloat162 h[2]; } u[4];
            #pragma unroll
            for (int g = 0; g < 4; ++g) {
                u[g].h[0] = __float22bfloat162_rn(make_float2(w[4 * g],     w[4 * g + 1]));
                u[g].h[1] = __float22bfloat162_rn(make_float2(w[4 * g + 2], w[4 * g + 3]));
            }
            #pragma unroll
            for (int g = 0; g < 4; ++g) {
                int gg = s * 4 + g;
                short4v vf0 = *(const short4v*)(VS + (size_t)(l32)      * VSTR + gg * 8 + h2 * 4);
                short4v vf1 = *(const short4v*)(VS + (size_t)(32 + l32) * VSTR + gg * 8 + h2 * 4);
                o0 = MFMA32x8(u[g].s, vf0, o0);
                o1 = MFMA32x8(u[g].s, vf1, o1);
            }
        }
        if (ph == 0) {
            __syncthreads();                           // barrier 2: done reading A
            #pragma unroll
            for (int i = 0; i < 8; ++i) {
                unsigned short* p = VS + (size_t)(chb + 2 * i) * VSTR + l32 * 8;
                *(ushort4v*)(p)     = *(ushort4v*)&vB[i];
                *(ushort4v*)(p + 4) = *((ushort4v*)&vB[i] + 1);
            }
            unsigned short* p = KL + (size_t)tid * KSTR;
            *(ushort4v*)(p)     = *(ushort4v*)&kB;
            *(ushort4v*)(p + 4) = *((ushort4v*)&kB + 1);
            __syncthreads();                           // barrier 3: B ready
        }
    }

    // ---- raw-layout full-line stores: uint per (r, lane)
    unsigned* au = accb + (((size_t)((b * KS + split) * 128 + qchunk * 4 + wave)) << 10);
    #pragma unroll
    for (int r = 0; r < 16; ++r)
        au[r * 64 + lane] = packu(o0[r], o1[r]);

    float ssum = (s0 + s1) + (s2 + s3);
    ssum += __shfl_xor(ssum, 32);
    if (lane < 32)
        sbuf[(size_t)(b * KS + split) * NN + n0 + l32] = ssum;
}

// ---------------------------------------------------------------------------
// Kernel 3: unscramble raw accb layout, reduce KS=8 splits, normalize,
// gamma*o + x.  Reads are coalesced uint4 (4KB per split-group); LDS
// transpose for coalesced out writes.  Grid: B*128 blocks (32 queries each).
// Mapping: q=(r&3)+8(r>>2)+4*(lane>>5), c=(lane&31)+32*half.
// ---------------------------------------------------------------------------
__global__ __launch_bounds__(256) void norm_kernel(
    const unsigned* __restrict__ accb, const float* __restrict__ sbuf,
    const float* __restrict__ x, const float* __restrict__ gamma,
    float* __restrict__ out)
{
    __shared__ float tile[32 * 65];
    __shared__ float stl[32];
    int blk = blockIdx.x;            // B * 128
    int b = blk >> 7;
    int g = blk & 127;
    int n0 = g * 32;
    int tid = threadIdx.x;

    if (tid < 32) {
        float st = 0.f;
        #pragma unroll
        for (int sp = 0; sp < KS; ++sp)
            st += sbuf[(size_t)(b * KS + sp) * NN + n0 + tid];
        stl[tid] = 1.0f / st;
    }

    int r = tid >> 4;
    int lane0 = (tid & 15) * 4;
    int h2 = lane0 >> 5;
    int qi = (r & 3) + 8 * (r >> 2) + 4 * h2;

    float alo[4], ahi[4];
    #pragma unroll
    for (int e = 0; e < 4; ++e) { alo[e] = 0.f; ahi[e] = 0.f; }
    #pragma unroll
    for (int sp = 0; sp < KS; ++sp) {
        const unsigned* base = accb + (((size_t)((b * KS + sp) * 128 + g)) << 10);
        uint4 v = *(const uint4*)(base + tid * 4);
        unsigned ws[4] = {v.x, v.y, v.z, v.w};
        #pragma unroll
        for (int e = 0; e < 4; ++e) {
            alo[e] += __uint_as_float(ws[e] << 16);
            ahi[e] += __uint_as_float(ws[e] & 0xFFFF0000u);
        }
    }
    #pragma unroll
    for (int e = 0; e < 4; ++e) {
        int cl = (lane0 + e) & 31;
        tile[qi * 65 + cl]      = alo[e];
        tile[qi * 65 + 32 + cl] = ahi[e];
    }
    __syncthreads();

    float gm = gamma[0];
    #pragma unroll
    for (int p = 0; p < 8; ++p) {
        int idx = p * 256 + tid;
        int c = idx >> 5, n_l = idx & 31;
        size_t xi = ((size_t)b * CC + c) * NN + n0 + n_l;
        out[xi] = gm * tile[n_l * 65 + c] * stl[n_l] + x[xi];
    }
}

// ---------------------------------------------------------------------------
extern "C" void kernel_launch(void* const* d_in, const int* in_sizes, int n_in,
                              void* d_out, int out_size, void* d_ws, size_t ws_size,
                              hipStream_t stream)
{
    const float* x     = (const float*)d_in[0];
    const float* Wq    = (const float*)d_in[1];
    const float* bq    = (const float*)d_in[2];
    const float* Wk    = (const float*)d_in[3];
    const float* bk    = (const float*)d_in[4];
    const float* Wv    = (const float*)d_in[5];
    const float* bv    = (const float*)d_in[6];
    const float* gamma = (const float*)d_in[7];
    float* out = (float*)d_out;

    float* ws = (float*)d_ws;
    size_t off = 0;
    unsigned short* qb = (unsigned short*)(ws + off); off += (size_t)BB * NN * DD / 2 + 64;
    unsigned short* kb = (unsigned short*)(ws + off); off += (size_t)BB * NN * DD / 2 + 64;
    unsigned short* vT = (unsigned short*)(ws + off); off += (size_t)BB * CC * NN / 2 + 64;
    unsigned* accb = (unsigned*)(ws + off); off += (size_t)BB * KS * NN * CC / 2;   // 16.8 MB
    float* sbuf = ws + off; off += (size_t)BB * KS * NN;

    qkv_kernel<<<BB * 3 * 32, 256, 0, stream>>>(x, Wq, bq, Wk, bk, Wv, bv, qb, kb, vT);
    flash_kernel<<<BB * (NN / 128) * KS, 256, 0, stream>>>(qb, kb, vT, accb, sbuf);
    norm_kernel<<<BB * 128, 256, 0, stream>>>(accb, sbuf, x, gamma, out);
}

// Round 12
// 105.176 us; speedup vs baseline: 1.0782x; 1.0782x over previous
//
#include <hip/hip_runtime.h>
#include <hip/hip_bf16.h>
#include <math.h>

#define BB 4
#define CC 64
#define DD 8
#define NN 4096
#define KS 16
#define KPS (NN / KS)          // 256 keys per split = ONE LDS stage
#define VSTR 260               // VS row stride (elems): 2-way-free b64 reads
#define KSTR 12                // KL row stride (elems)
#define LOG2E 1.44269504088896340736f

typedef __attribute__((ext_vector_type(4))) short short4v;      // 4 bf16
typedef __attribute__((ext_vector_type(4))) unsigned short ushort4v;
typedef __attribute__((ext_vector_type(8))) unsigned short ushort8;  // 16B
typedef __attribute__((ext_vector_type(16))) float f32x16;

#if defined(__HIP_DEVICE_COMPILE__)
  #if __has_builtin(__builtin_amdgcn_mfma_f32_32x32x8bf16_1k)
    #define MFMA32x8(A, B, C) __builtin_amdgcn_mfma_f32_32x32x8bf16_1k(A, B, C, 0, 0, 0)
  #elif __has_builtin(__builtin_amdgcn_mfma_f32_32x32x8_bf16)
    #define MFMA32x8(A, B, C) __builtin_amdgcn_mfma_f32_32x32x8_bf16(A, B, C, 0, 0, 0)
  #else
    #error "no 32x32x8 bf16 MFMA builtin in device pass"
  #endif
  #if __has_builtin(__builtin_amdgcn_exp2f)
    #define EXP2(x) __builtin_amdgcn_exp2f(x)
  #else
    #define EXP2(x) exp2f(x)
  #endif
#else
  static __device__ __host__ inline f32x16 MFMA32x8(short4v, short4v, f32x16 c) { return c; }
  #define EXP2(x) exp2f(x)
#endif

static __device__ inline short4v pack4(float a, float b, float c, float d) {
    union { short4v s; __hip_bfloat162 h[2]; } u;
    u.h[0] = __float22bfloat162_rn(make_float2(a, b));
    u.h[1] = __float22bfloat162_rn(make_float2(c, d));
    return u.s;
}
static __device__ inline unsigned packu(float lo, float hi) {
    union { __hip_bfloat162 h; unsigned u; } t;
    t.h = __float22bfloat162_rn(make_float2(lo, hi));
    return t.u;
}

// ---------------------------------------------------------------------------
// Kernel 1: qkv as MFMA GEMM (unchanged from R8-R11).
// ---------------------------------------------------------------------------
__global__ __launch_bounds__(256) void qkv_kernel(
    const float* __restrict__ x,  const float* __restrict__ Wq, const float* __restrict__ bq,
    const float* __restrict__ Wk, const float* __restrict__ bk,
    const float* __restrict__ Wv, const float* __restrict__ bv,
    unsigned short* __restrict__ qb, unsigned short* __restrict__ kb,
    unsigned short* __restrict__ vT)
{
    __shared__ unsigned short LQ[128 * 8];
    __shared__ unsigned short LK[128 * 8];

    int tid = threadIdx.x;
    int wave = tid >> 6, lane = tid & 63;
    int l32 = lane & 31, h2 = lane >> 5;

    int blk = blockIdx.x;
    int b = blk & (BB - 1);
    int r2 = blk >> 2;
    int rt = r2 % 3;
    int ng = r2 / 3;
    int n0 = ng * 128 + wave * 32;

    short4v af[8];
    #pragma unroll
    for (int s = 0; s < 8; ++s) {
        float4 w4;
        if (rt < 2) {
            w4 = *(const float4*)(Wv + (size_t)(rt * 32 + l32) * CC + s * 8 + 4 * h2);
        } else if (l32 < 8) {
            w4 = *(const float4*)(Wq + (size_t)l32 * CC + s * 8 + 4 * h2);
        } else if (l32 < 16) {
            w4 = *(const float4*)(Wk + (size_t)(l32 - 8) * CC + s * 8 + 4 * h2);
        } else {
            w4 = make_float4(0.f, 0.f, 0.f, 0.f);
        }
        af[s] = pack4(w4.x, w4.y, w4.z, w4.w);
    }

    const float* xb = x + (size_t)b * CC * NN + n0 + l32;
    short4v bf[8];
    #pragma unroll
    for (int s = 0; s < 8; ++s) {
        int c0 = s * 8 + 4 * h2;
        float x0 = xb[(size_t)(c0 + 0) * NN];
        float x1 = xb[(size_t)(c0 + 1) * NN];
        float x2 = xb[(size_t)(c0 + 2) * NN];
        float x3 = xb[(size_t)(c0 + 3) * NN];
        bf[s] = pack4(x0, x1, x2, x3);
    }

    f32x16 acc;
    #pragma unroll
    for (int r = 0; r < 16; ++r) acc[r] = 0.f;
    #pragma unroll
    for (int s = 0; s < 8; ++s)
        acc = MFMA32x8(af[s], bf[s], acc);

    if (rt < 2) {
        #pragma unroll
        for (int r = 0; r < 16; ++r) {
            int row = rt * 32 + (r & 3) + 8 * (r >> 2) + 4 * h2;
            float val = acc[r] + bv[row];
            __hip_bfloat16 hv = __float2bfloat16(val);
            vT[((size_t)b * CC + row) * NN + n0 + l32] = *(unsigned short*)&hv;
        }
    } else {
        short4v qp = pack4((acc[0] + bq[0 + 4 * h2]) * LOG2E,
                           (acc[1] + bq[1 + 4 * h2]) * LOG2E,
                           (acc[2] + bq[2 + 4 * h2]) * LOG2E,
                           (acc[3] + bq[3 + 4 * h2]) * LOG2E);
        short4v kp = pack4(acc[4] + bk[0 + 4 * h2],
                           acc[5] + bk[1 + 4 * h2],
                           acc[6] + bk[2 + 4 * h2],
                           acc[7] + bk[3 + 4 * h2]);
        int nl = wave * 32 + l32;
        *(short4v*)(LQ + (size_t)nl * 8 + 4 * h2) = qp;
        *(short4v*)(LK + (size_t)nl * 8 + 4 * h2) = kp;
        __syncthreads();
        if (tid < 128) {
            ushort8 row = *(const ushort8*)(LQ + (size_t)tid * 8);
            *(ushort8*)(qb + ((size_t)b * NN + ng * 128 + tid) * 8) = row;
        } else {
            int t = tid - 128;
            ushort8 row = *(const ushort8*)(LK + (size_t)t * 8);
            *(ushort8*)(kb + ((size_t)b * NN + ng * 128 + t) * 8) = row;
        }
    }
}

// ---------------------------------------------------------------------------
// Kernel 2: MFMA flash, occupancy-first restructure.
// 512-thread blocks (8 waves = 256 queries) share ONE 256-key LDS stage
// (KS=16 splits): 5 global loads/thread -> ds_write -> ONE barrier ->
// 8 compute subs -> full-line stores.  38.5KB LDS x 4 blocks/CU x 8 waves
// = 32 waves/CU (8/SIMD) -- vs ~1.25/SIMD effective in R9-R11, whose
// ~500cyc/sub serial chain x 16 subs explained the invariant ~40us.
// Grid: BB * 16 qchunks * KS = 1024 blocks.
// ---------------------------------------------------------------------------
__global__ __launch_bounds__(512, 8) void flash_kernel(
    const unsigned short* __restrict__ qb, const unsigned short* __restrict__ kb,
    const unsigned short* __restrict__ vT, unsigned* __restrict__ accb,
    float* __restrict__ sbuf)
{
    __shared__ unsigned short VS[64 * VSTR];   // 256 keys x 64 ch, 33280 B
    __shared__ unsigned short KL[256 * KSTR];  //  6144 B
    int tid = threadIdx.x;
    int wave = tid >> 6, lane = tid & 63;
    int l32 = lane & 31, h2 = lane >> 5;

    int blk = blockIdx.x;            // batch in low 2 bits -> XCD locality
    int b = blk & (BB - 1);
    int rest = blk >> 2;
    int split = rest & (KS - 1);
    int qchunk = rest >> 4;
    int n0 = qchunk * 256 + wave * 32;

    short4v qf = *(const short4v*)(qb + ((size_t)b * NN + n0 + l32) * DD + h2 * 4);

    const unsigned short* kbb = kb + (size_t)b * NN * DD;
    const unsigned short* vbb = vT + (size_t)b * CC * NN;
    int m0 = split * KPS;

    // ---- stage: thread t -> channel t>>3, key segment (t&7)*32 (32 keys)
    int ch = tid >> 3, ks0 = (tid & 7) * 32;
    {
        const unsigned short* vg = vbb + (size_t)ch * NN + m0 + ks0;
        ushort8 v0 = *(const ushort8*)(vg);
        ushort8 v1 = *(const ushort8*)(vg + 8);
        ushort8 v2 = *(const ushort8*)(vg + 16);
        ushort8 v3 = *(const ushort8*)(vg + 24);
        ushort8 kA = {0,0,0,0,0,0,0,0};
        if (tid < 256) kA = *(const ushort8*)(kbb + (size_t)(m0 + tid) * DD);

        unsigned short* vp = VS + (size_t)ch * VSTR + ks0;
        *(ushort4v*)(vp)      = *(ushort4v*)&v0;
        *(ushort4v*)(vp + 4)  = *((ushort4v*)&v0 + 1);
        *(ushort4v*)(vp + 8)  = *(ushort4v*)&v1;
        *(ushort4v*)(vp + 12) = *((ushort4v*)&v1 + 1);
        *(ushort4v*)(vp + 16) = *(ushort4v*)&v2;
        *(ushort4v*)(vp + 20) = *((ushort4v*)&v2 + 1);
        *(ushort4v*)(vp + 24) = *(ushort4v*)&v3;
        *(ushort4v*)(vp + 28) = *((ushort4v*)&v3 + 1);
        if (tid < 256) {
            unsigned short* p = KL + (size_t)tid * KSTR;
            *(ushort4v*)(p)     = *(ushort4v*)&kA;
            *(ushort4v*)(p + 4) = *((ushort4v*)&kA + 1);
        }
    }
    __syncthreads();                           // the ONLY barrier

    f32x16 o0, o1, zz;
    #pragma unroll
    for (int r = 0; r < 16; ++r) { o0[r] = 0.f; o1[r] = 0.f; zz[r] = 0.f; }
    float s0 = 0.f, s1 = 0.f, s2 = 0.f, s3 = 0.f;

    #pragma unroll
    for (int s = 0; s < 8; ++s) {
        short4v kf = *(const short4v*)(KL + (size_t)(s * 32 + l32) * KSTR + h2 * 4);
        f32x16 st = MFMA32x8(kf, qf, zz);
        float w[16];
        #pragma unroll
        for (int r = 0; r < 16; ++r) w[r] = EXP2(st[r]);
        s0 += (w[0] + w[1]) + (w[2] + w[3]);
        s1 += (w[4] + w[5]) + (w[6] + w[7]);
        s2 += (w[8] + w[9]) + (w[10] + w[11]);
        s3 += (w[12] + w[13]) + (w[14] + w[15]);

        union { short4v s; __hip_bfloat162 h[2]; } u[4];
        #pragma unroll
        for (int g = 0; g < 4; ++g) {
            u[g].h[0] = __float22bfloat162_rn(make_float2(w[4 * g],     w[4 * g + 1]));
            u[g].h[1] = __float22bfloat162_rn(make_float2(w[4 * g + 2], w[4 * g + 3]));
        }
        #pragma unroll
        for (int g = 0; g < 4; ++g) {
            int gg = s * 4 + g;
            short4v vf0 = *(const short4v*)(VS + (size_t)(l32)      * VSTR + gg * 8 + h2 * 4);
            short4v vf1 = *(const short4v*)(VS + (size_t)(32 + l32) * VSTR + gg * 8 + h2 * 4);
            o0 = MFMA32x8(u[g].s, vf0, o0);
            o1 = MFMA32x8(u[g].s, vf1, o1);
        }
    }

    // ---- raw-layout full-line stores: uint = bf162(o0[r],o1[r])
    unsigned* au = accb + (((size_t)((b * KS + split) * 128 + qchunk * 8 + wave)) << 10);
    #pragma unroll
    for (int r = 0; r < 16; ++r)
        au[r * 64 + lane] = packu(o0[r], o1[r]);

    float ssum = (s0 + s1) + (s2 + s3);
    ssum += __shfl_xor(ssum, 32);
    if (lane < 32)
        sbuf[(size_t)(b * KS + split) * NN + n0 + l32] = ssum;
}

// ---------------------------------------------------------------------------
// Kernel 3: unscramble raw accb, reduce KS=16 splits, normalize, gamma*o + x.
// Coalesced uint4 reads; LDS transpose for coalesced out writes.
// Mapping: q=(r&3)+8(r>>2)+4*(lane>>5), c=(lane&31)+32*half.
// Grid: B*128 blocks (32 queries each).
// ---------------------------------------------------------------------------
__global__ __launch_bounds__(256) void norm_kernel(
    const unsigned* __restrict__ accb, const float* __restrict__ sbuf,
    const float* __restrict__ x, const float* __restrict__ gamma,
    float* __restrict__ out)
{
    __shared__ float tile[32 * 65];
    __shared__ float stl[32];
    int blk = blockIdx.x;            // B * 128
    int b = blk >> 7;
    int g = blk & 127;
    int n0 = g * 32;
    int tid = threadIdx.x;

    if (tid < 32) {
        float st = 0.f;
        #pragma unroll
        for (int sp = 0; sp < KS; ++sp)
            st += sbuf[(size_t)(b * KS + sp) * NN + n0 + tid];
        stl[tid] = 1.0f / st;
    }

    int r = tid >> 4;
    int lane0 = (tid & 15) * 4;
    int h2 = lane0 >> 5;
    int qi = (r & 3) + 8 * (r >> 2) + 4 * h2;

    float alo[4], ahi[4];
    #pragma unroll
    for (int e = 0; e < 4; ++e) { alo[e] = 0.f; ahi[e] = 0.f; }
    #pragma unroll
    for (int sp = 0; sp < KS; ++sp) {
        const unsigned* base = accb + (((size_t)((b * KS + sp) * 128 + g)) << 10);
        uint4 v = *(const uint4*)(base + tid * 4);
        unsigned ws[4] = {v.x, v.y, v.z, v.w};
        #pragma unroll
        for (int e = 0; e < 4; ++e) {
            alo[e] += __uint_as_float(ws[e] << 16);
            ahi[e] += __uint_as_float(ws[e] & 0xFFFF0000u);
        }
    }
    #pragma unroll
    for (int e = 0; e < 4; ++e) {
        int cl = (lane0 + e) & 31;
        tile[qi * 65 + cl]      = alo[e];
        tile[qi * 65 + 32 + cl] = ahi[e];
    }
    __syncthreads();

    float gm = gamma[0];
    #pragma unroll
    for (int p = 0; p < 8; ++p) {
        int idx = p * 256 + tid;
        int c = idx >> 5, n_l = idx & 31;
        size_t xi = ((size_t)b * CC + c) * NN + n0 + n_l;
        out[xi] = gm * tile[n_l * 65 + c] * stl[n_l] + x[xi];
    }
}

// ---------------------------------------------------------------------------
extern "C" void kernel_launch(void* const* d_in, const int* in_sizes, int n_in,
                              void* d_out, int out_size, void* d_ws, size_t ws_size,
                              hipStream_t stream)
{
    const float* x     = (const float*)d_in[0];
    const float* Wq    = (const float*)d_in[1];
    const float* bq    = (const float*)d_in[2];
    const float* Wk    = (const float*)d_in[3];
    const float* bk    = (const float*)d_in[4];
    const float* Wv    = (const float*)d_in[5];
    const float* bv    = (const float*)d_in[6];
    const float* gamma = (const float*)d_in[7];
    float* out = (float*)d_out;

    float* ws = (float*)d_ws;
    size_t off = 0;
    unsigned short* qb = (unsigned short*)(ws + off); off += (size_t)BB * NN * DD / 2 + 64;
    unsigned short* kb = (unsigned short*)(ws + off); off += (size_t)BB * NN * DD / 2 + 64;
    unsigned short* vT = (unsigned short*)(ws + off); off += (size_t)BB * CC * NN / 2 + 64;
    unsigned* accb = (unsigned*)(ws + off); off += (size_t)BB * KS * NN * CC / 2;   // 33.5 MB
    float* sbuf = ws + off; off += (size_t)BB * KS * NN;

    qkv_kernel<<<BB * 3 * 32, 256, 0, stream>>>(x, Wq, bq, Wk, bk, Wv, bv, qb, kb, vT);
    flash_kernel<<<BB * 16 * KS, 512, 0, stream>>>(qb, kb, vT, accb, sbuf);
    norm_kernel<<<BB * 128, 256, 0, stream>>>(accb, sbuf, x, gamma, out);
}

// Round 13
// 101.458 us; speedup vs baseline: 1.1177x; 1.0366x over previous
//
#include <hip/hip_runtime.h>
#include <hip/hip_bf16.h>
#include <math.h>

#define BB 4
#define CC 64
#define DD 8
#define NN 4096
#define KS 16
#define KPS (NN / KS)          // 256 keys per split = ONE LDS stage
#define VSTR 260               // VS row stride (elems): 2-way-free b64 reads
#define KSTR 12                // KL row stride (elems)
#define LOG2E 1.44269504088896340736f

typedef __attribute__((ext_vector_type(4))) short short4v;      // 4 bf16
typedef __attribute__((ext_vector_type(4))) unsigned short ushort4v;
typedef __attribute__((ext_vector_type(8))) unsigned short ushort8;  // 16B
typedef __attribute__((ext_vector_type(16))) float f32x16;

#if defined(__HIP_DEVICE_COMPILE__)
  #if __has_builtin(__builtin_amdgcn_mfma_f32_32x32x8bf16_1k)
    #define MFMA32x8(A, B, C) __builtin_amdgcn_mfma_f32_32x32x8bf16_1k(A, B, C, 0, 0, 0)
  #elif __has_builtin(__builtin_amdgcn_mfma_f32_32x32x8_bf16)
    #define MFMA32x8(A, B, C) __builtin_amdgcn_mfma_f32_32x32x8_bf16(A, B, C, 0, 0, 0)
  #else
    #error "no 32x32x8 bf16 MFMA builtin in device pass"
  #endif
  #if __has_builtin(__builtin_amdgcn_exp2f)
    #define EXP2(x) __builtin_amdgcn_exp2f(x)
  #else
    #define EXP2(x) exp2f(x)
  #endif
#else
  static __device__ __host__ inline f32x16 MFMA32x8(short4v, short4v, f32x16 c) { return c; }
  #define EXP2(x) exp2f(x)
#endif

static __device__ inline short4v pack4(float a, float b, float c, float d) {
    union { short4v s; __hip_bfloat162 h[2]; } u;
    u.h[0] = __float22bfloat162_rn(make_float2(a, b));
    u.h[1] = __float22bfloat162_rn(make_float2(c, d));
    return u.s;
}
static __device__ inline unsigned packu(float lo, float hi) {
    union { __hip_bfloat162 h; unsigned u; } t;
    t.h = __float22bfloat162_rn(make_float2(lo, hi));
    return t.u;
}

// ---------------------------------------------------------------------------
// Kernel 1: qkv as MFMA GEMM (unchanged from R8-R12).
// ---------------------------------------------------------------------------
__global__ __launch_bounds__(256) void qkv_kernel(
    const float* __restrict__ x,  const float* __restrict__ Wq, const float* __restrict__ bq,
    const float* __restrict__ Wk, const float* __restrict__ bk,
    const float* __restrict__ Wv, const float* __restrict__ bv,
    unsigned short* __restrict__ qb, unsigned short* __restrict__ kb,
    unsigned short* __restrict__ vT)
{
    __shared__ unsigned short LQ[128 * 8];
    __shared__ unsigned short LK[128 * 8];

    int tid = threadIdx.x;
    int wave = tid >> 6, lane = tid & 63;
    int l32 = lane & 31, h2 = lane >> 5;

    int blk = blockIdx.x;
    int b = blk & (BB - 1);
    int r2 = blk >> 2;
    int rt = r2 % 3;
    int ng = r2 / 3;
    int n0 = ng * 128 + wave * 32;

    short4v af[8];
    #pragma unroll
    for (int s = 0; s < 8; ++s) {
        float4 w4;
        if (rt < 2) {
            w4 = *(const float4*)(Wv + (size_t)(rt * 32 + l32) * CC + s * 8 + 4 * h2);
        } else if (l32 < 8) {
            w4 = *(const float4*)(Wq + (size_t)l32 * CC + s * 8 + 4 * h2);
        } else if (l32 < 16) {
            w4 = *(const float4*)(Wk + (size_t)(l32 - 8) * CC + s * 8 + 4 * h2);
        } else {
            w4 = make_float4(0.f, 0.f, 0.f, 0.f);
        }
        af[s] = pack4(w4.x, w4.y, w4.z, w4.w);
    }

    const float* xb = x + (size_t)b * CC * NN + n0 + l32;
    short4v bf[8];
    #pragma unroll
    for (int s = 0; s < 8; ++s) {
        int c0 = s * 8 + 4 * h2;
        float x0 = xb[(size_t)(c0 + 0) * NN];
        float x1 = xb[(size_t)(c0 + 1) * NN];
        float x2 = xb[(size_t)(c0 + 2) * NN];
        float x3 = xb[(size_t)(c0 + 3) * NN];
        bf[s] = pack4(x0, x1, x2, x3);
    }

    f32x16 acc;
    #pragma unroll
    for (int r = 0; r < 16; ++r) acc[r] = 0.f;
    #pragma unroll
    for (int s = 0; s < 8; ++s)
        acc = MFMA32x8(af[s], bf[s], acc);

    if (rt < 2) {
        #pragma unroll
        for (int r = 0; r < 16; ++r) {
            int row = rt * 32 + (r & 3) + 8 * (r >> 2) + 4 * h2;
            float val = acc[r] + bv[row];
            __hip_bfloat16 hv = __float2bfloat16(val);
            vT[((size_t)b * CC + row) * NN + n0 + l32] = *(unsigned short*)&hv;
        }
    } else {
        short4v qp = pack4((acc[0] + bq[0 + 4 * h2]) * LOG2E,
                           (acc[1] + bq[1 + 4 * h2]) * LOG2E,
                           (acc[2] + bq[2 + 4 * h2]) * LOG2E,
                           (acc[3] + bq[3 + 4 * h2]) * LOG2E);
        short4v kp = pack4(acc[4] + bk[0 + 4 * h2],
                           acc[5] + bk[1 + 4 * h2],
                           acc[6] + bk[2 + 4 * h2],
                           acc[7] + bk[3 + 4 * h2]);
        int nl = wave * 32 + l32;
        *(short4v*)(LQ + (size_t)nl * 8 + 4 * h2) = qp;
        *(short4v*)(LK + (size_t)nl * 8 + 4 * h2) = kp;
        __syncthreads();
        if (tid < 128) {
            ushort8 row = *(const ushort8*)(LQ + (size_t)tid * 8);
            *(ushort8*)(qb + ((size_t)b * NN + ng * 128 + tid) * 8) = row;
        } else {
            int t = tid - 128;
            ushort8 row = *(const ushort8*)(LK + (size_t)t * 8);
            *(ushort8*)(kb + ((size_t)b * NN + ng * 128 + t) * 8) = row;
        }
    }
}

// ---------------------------------------------------------------------------
// Kernel 2: MFMA flash (R12 structure; launch_bounds relaxed 8->6 waves/EU).
// R12's (512,8) forced VGPR<=64 while adding 8 ushort8 staging regs -> likely
// scratch spills.  (512,6) caps ~85 VGPR: staging fits, no spill; 3 blocks/CU
// x 8 waves = 24 waves/CU.  512-thr blocks (8 waves = 256 q) share ONE
// 256-key LDS stage; 1 barrier; full-line raw-layout stores.
// Grid: BB * 16 qchunks * KS = 1024 blocks.
// ---------------------------------------------------------------------------
__global__ __launch_bounds__(512, 6) void flash_kernel(
    const unsigned short* __restrict__ qb, const unsigned short* __restrict__ kb,
    const unsigned short* __restrict__ vT, unsigned* __restrict__ accb,
    float* __restrict__ sbuf)
{
    __shared__ unsigned short VS[64 * VSTR];   // 256 keys x 64 ch, 33280 B
    __shared__ unsigned short KL[256 * KSTR];  //  6144 B
    int tid = threadIdx.x;
    int wave = tid >> 6, lane = tid & 63;
    int l32 = lane & 31, h2 = lane >> 5;

    int blk = blockIdx.x;            // batch in low 2 bits -> XCD locality
    int b = blk & (BB - 1);
    int rest = blk >> 2;
    int split = rest & (KS - 1);
    int qchunk = rest >> 4;
    int n0 = qchunk * 256 + wave * 32;

    short4v qf = *(const short4v*)(qb + ((size_t)b * NN + n0 + l32) * DD + h2 * 4);

    const unsigned short* kbb = kb + (size_t)b * NN * DD;
    const unsigned short* vbb = vT + (size_t)b * CC * NN;
    int m0 = split * KPS;

    // ---- stage: thread t -> channel t>>3, key segment (t&7)*32 (32 keys)
    int ch = tid >> 3, ks0 = (tid & 7) * 32;
    {
        const unsigned short* vg = vbb + (size_t)ch * NN + m0 + ks0;
        ushort8 v0 = *(const ushort8*)(vg);
        ushort8 v1 = *(const ushort8*)(vg + 8);
        ushort8 v2 = *(const ushort8*)(vg + 16);
        ushort8 v3 = *(const ushort8*)(vg + 24);
        ushort8 kA = {0,0,0,0,0,0,0,0};
        if (tid < 256) kA = *(const ushort8*)(kbb + (size_t)(m0 + tid) * DD);

        unsigned short* vp = VS + (size_t)ch * VSTR + ks0;
        *(ushort4v*)(vp)      = *(ushort4v*)&v0;
        *(ushort4v*)(vp + 4)  = *((ushort4v*)&v0 + 1);
        *(ushort4v*)(vp + 8)  = *(ushort4v*)&v1;
        *(ushort4v*)(vp + 12) = *((ushort4v*)&v1 + 1);
        *(ushort4v*)(vp + 16) = *(ushort4v*)&v2;
        *(ushort4v*)(vp + 20) = *((ushort4v*)&v2 + 1);
        *(ushort4v*)(vp + 24) = *(ushort4v*)&v3;
        *(ushort4v*)(vp + 28) = *((ushort4v*)&v3 + 1);
        if (tid < 256) {
            unsigned short* p = KL + (size_t)tid * KSTR;
            *(ushort4v*)(p)     = *(ushort4v*)&kA;
            *(ushort4v*)(p + 4) = *((ushort4v*)&kA + 1);
        }
    }
    __syncthreads();                           // the ONLY barrier

    f32x16 o0, o1, zz;
    #pragma unroll
    for (int r = 0; r < 16; ++r) { o0[r] = 0.f; o1[r] = 0.f; zz[r] = 0.f; }
    float s0 = 0.f, s1 = 0.f, s2 = 0.f, s3 = 0.f;

    #pragma unroll
    for (int s = 0; s < 8; ++s) {
        short4v kf = *(const short4v*)(KL + (size_t)(s * 32 + l32) * KSTR + h2 * 4);
        f32x16 st = MFMA32x8(kf, qf, zz);
        float w[16];
        #pragma unroll
        for (int r = 0; r < 16; ++r) w[r] = EXP2(st[r]);
        s0 += (w[0] + w[1]) + (w[2] + w[3]);
        s1 += (w[4] + w[5]) + (w[6] + w[7]);
        s2 += (w[8] + w[9]) + (w[10] + w[11]);
        s3 += (w[12] + w[13]) + (w[14] + w[15]);

        union { short4v s; __hip_bfloat162 h[2]; } u[4];
        #pragma unroll
        for (int g = 0; g < 4; ++g) {
            u[g].h[0] = __float22bfloat162_rn(make_float2(w[4 * g],     w[4 * g + 1]));
            u[g].h[1] = __float22bfloat162_rn(make_float2(w[4 * g + 2], w[4 * g + 3]));
        }
        #pragma unroll
        for (int g = 0; g < 4; ++g) {
            int gg = s * 4 + g;
            short4v vf0 = *(const short4v*)(VS + (size_t)(l32)      * VSTR + gg * 8 + h2 * 4);
            short4v vf1 = *(const short4v*)(VS + (size_t)(32 + l32) * VSTR + gg * 8 + h2 * 4);
            o0 = MFMA32x8(u[g].s, vf0, o0);
            o1 = MFMA32x8(u[g].s, vf1, o1);
        }
    }

    // ---- raw-layout full-line stores: uint = bf162(o0[r],o1[r])
    unsigned* au = accb + (((size_t)((b * KS + split) * 128 + qchunk * 8 + wave)) << 10);
    #pragma unroll
    for (int r = 0; r < 16; ++r)
        au[r * 64 + lane] = packu(o0[r], o1[r]);

    float ssum = (s0 + s1) + (s2 + s3);
    ssum += __shfl_xor(ssum, 32);
    if (lane < 32)
        sbuf[(size_t)(b * KS + split) * NN + n0 + l32] = ssum;
}

// ---------------------------------------------------------------------------
// Kernel 3 (REWRITE): streaming split-reduce + normalize + residual.
// Block owns 16 queries (half a 32-q group: r<8 <-> q<16 in the raw layout).
// 8 passes, each reading 2 splits as CONTIGUOUS uint4 runs (4KB/block/pass);
// split-halves (t<128 / t>=128 hold even/odd sp) combined in LDS; coalesced
// out/x passes.  Grid: B*256 = 1024 blocks.
// ---------------------------------------------------------------------------
__global__ __launch_bounds__(256) void norm_kernel(
    const unsigned* __restrict__ accb, const float* __restrict__ sbuf,
    const float* __restrict__ x, const float* __restrict__ gamma,
    float* __restrict__ out)
{
    __shared__ float tile[16 * 65];
    __shared__ float stl[16];
    int blk = blockIdx.x;            // B * 256
    int b = blk >> 8;
    int h = blk & 255;
    int g32 = h >> 1;                // 32-query group
    int qhalf = h & 1;               // low/high 16 queries of the group
    int n0 = g32 * 32 + qhalf * 16;
    int tid = threadIdx.x;

    if (tid < 16) {
        float st = 0.f;
        #pragma unroll
        for (int sp = 0; sp < KS; ++sp)
            st += sbuf[(size_t)(b * KS + sp) * NN + n0 + tid];
        stl[tid] = 1.0f / st;
    }

    int spoff = tid >> 7;            // 0/1: even/odd split of each pass-pair
    int u = tid & 127;
    int rl = u >> 4;                 // r_local 0..7
    int lane0 = (u & 15) * 4;

    float alo[4], ahi[4];
    #pragma unroll
    for (int e = 0; e < 4; ++e) { alo[e] = 0.f; ahi[e] = 0.f; }
    #pragma unroll
    for (int p = 0; p < 8; ++p) {
        int sp = p * 2 + spoff;
        const unsigned* base = accb + (((size_t)((b * KS + sp) * 128 + g32)) << 10)
                             + qhalf * 512;
        uint4 v = *(const uint4*)(base + u * 4);
        unsigned wv[4] = {v.x, v.y, v.z, v.w};
        #pragma unroll
        for (int e = 0; e < 4; ++e) {
            alo[e] += __uint_as_float(wv[e] << 16);
            ahi[e] += __uint_as_float(wv[e] & 0xFFFF0000u);
        }
    }

    // combine the two split-halves in LDS
    // q_local = (rl&3) + 8*((rl>>2)&1) + 4*(lane>>5);  c = (lane&31) + 32*half
    #pragma unroll
    for (int e = 0; e < 4; ++e) {
        int lane = lane0 + e;
        int h2 = lane >> 5, l32 = lane & 31;
        int ql = (rl & 3) + 8 * ((rl >> 2) & 1) + 4 * h2;
        if (tid < 128) {
            tile[ql * 65 + l32]      = alo[e];
            tile[ql * 65 + 32 + l32] = ahi[e];
        }
    }
    __syncthreads();
    #pragma unroll
    for (int e = 0; e < 4; ++e) {
        int lane = lane0 + e;
        int h2 = lane >> 5, l32 = lane & 31;
        int ql = (rl & 3) + 8 * ((rl >> 2) & 1) + 4 * h2;
        if (tid >= 128) {
            tile[ql * 65 + l32]      += alo[e];
            tile[ql * 65 + 32 + l32] += ahi[e];
        }
    }
    __syncthreads();

    float gm = gamma[0];
    #pragma unroll
    for (int p2 = 0; p2 < 4; ++p2) {
        int idx = p2 * 256 + tid;
        int c = idx >> 4, ql = idx & 15;
        size_t xi = ((size_t)b * CC + c) * NN + n0 + ql;
        out[xi] = gm * tile[ql * 65 + c] * stl[ql] + x[xi];
    }
}

// ---------------------------------------------------------------------------
extern "C" void kernel_launch(void* const* d_in, const int* in_sizes, int n_in,
                              void* d_out, int out_size, void* d_ws, size_t ws_size,
                              hipStream_t stream)
{
    const float* x     = (const float*)d_in[0];
    const float* Wq    = (const float*)d_in[1];
    const float* bq    = (const float*)d_in[2];
    const float* Wk    = (const float*)d_in[3];
    const float* bk    = (const float*)d_in[4];
    const float* Wv    = (const float*)d_in[5];
    const float* bv    = (const float*)d_in[6];
    const float* gamma = (const float*)d_in[7];
    float* out = (float*)d_out;

    float* ws = (float*)d_ws;
    size_t off = 0;
    unsigned short* qb = (unsigned short*)(ws + off); off += (size_t)BB * NN * DD / 2 + 64;
    unsigned short* kb = (unsigned short*)(ws + off); off += (size_t)BB * NN * DD / 2 + 64;
    unsigned short* vT = (unsigned short*)(ws + off); off += (size_t)BB * CC * NN / 2 + 64;
    unsigned* accb = (unsigned*)(ws + off); off += (size_t)BB * KS * NN * CC / 2;   // 33.5 MB
    float* sbuf = ws + off; off += (size_t)BB * KS * NN;

    qkv_kernel<<<BB * 3 * 32, 256, 0, stream>>>(x, Wq, bq, Wk, bk, Wv, bv, qb, kb, vT);
    flash_kernel<<<BB * 16 * KS, 512, 0, stream>>>(qb, kb, vT, accb, sbuf);
    norm_kernel<<<BB * 256, 256, 0, stream>>>(accb, sbuf, x, gamma, out);
}